// Round 9
// baseline (508.911 us; speedup 1.0000x reference)
//
#include <hip/hip_runtime.h>
#include <hip/hip_bf16.h>

#define GRID_W 64
#define NPTS   4096
#define BATCH  8
#define DD     32
#define DIN    80
#define HID    128
#define SH_STRIDE 136              // ushort stride (17*16B) -> conflict-free b128
#define SQ_STRIDE 36               // f32 stride for LDS state rows
#define HB     40                  // ushort stride for bf16 halo rows (80B, 16B-mult)
#define NBLK   512                 // one grid-row per block
#define NSTEP  34                  // fallback half-step count
#define NFULL  17                  // max full steps for tf <= 4.0
#define SPIN_CAP 8192              // timeout => terminate w/ wrong data, never hang
// ws layout: [unused 128KB] | fragments | ebuf (tagged, PARITY double-buffered)
#define OFF_F1Q 131072
#define OFF_F2Q (OFF_F1Q + 24*64*16)
#define OFF_F1P (OFF_F2Q + 8*64*16)
#define OFF_F2P (OFF_F1P + 24*64*16)
#define OFF_EBUF 262144
// tagged ebuf: per parity, per (b,row,pt): 2 halves x 12 u64. u64=[3 bf16|tag].
// parity p holds publications with tag t where t&1 == p. 2 x 6 MB = 12 MB.
#define EB_PAR ((size_t)NBLK * 64 * 24)
#define WS_NEED ((size_t)OFF_EBUF + 2 * EB_PAR * 8)

typedef __attribute__((ext_vector_type(8))) short short8;
typedef __attribute__((ext_vector_type(4))) float f32x4;
typedef unsigned long long u64;

__device__ __forceinline__ ushort f2bf(float v) {
    __hip_bfloat16 h = __float2bfloat16(v);
    return __builtin_bit_cast(ushort, h);
}
__device__ __forceinline__ uint packbf(float a, float b) {
    return (uint)f2bf(a) | ((uint)f2bf(b) << 16);
}
__device__ __forceinline__ short8 pack8(float4 a, float4 b) {
    union { uint u[4]; short8 s; } t;
    t.u[0] = packbf(a.x, a.y); t.u[1] = packbf(a.z, a.w);
    t.u[2] = packbf(b.x, b.y); t.u[3] = packbf(b.z, b.w);
    return t.s;
}
__device__ __forceinline__ float bf2f(ushort u) {
    union { uint i; float f; } t; t.i = ((uint)u) << 16; return t.f;
}
// 3 tagged u64 (3 bf16 each, dims 0..7 of a quad region) -> one short8
__device__ __forceinline__ short8 u3_to_s8(u64 a, u64 b, u64 c) {
    union { uint w[4]; short8 s; } t;
    t.w[0] = (uint)a;
    t.w[1] = (uint)((a >> 32) & 0xFFFFull) | (((uint)(b & 0xFFFFull)) << 16);
    t.w[2] = (uint)(b >> 16);
    t.w[3] = (uint)c;
    return t.s;
}

// System-scope (LLC coherence point) u64 accessors. Single-scope everywhere
// (r1-r3: mixing sc0-cached and system traffic on shared lines is poison).
__device__ __forceinline__ u64 ld_sys64(const u64* p) {
    return __hip_atomic_load(p, __ATOMIC_RELAXED, __HIP_MEMORY_SCOPE_SYSTEM);
}
__device__ __forceinline__ void st_sys64(u64* p, u64 v) {
    __hip_atomic_store(p, v, __ATOMIC_RELAXED, __HIP_MEMORY_SCOPE_SYSTEM);
}

// ---- ONE setup kernel: copy x->out, tagged ebuf (parity 0: tag 0 data;
// parity 1: tag 0xFFFF = never-valid, kills cross-replay staleness),
// pack weight fragments. Kernel-boundary writeback -> LLC-visible.
__global__ void setup_all(const float* __restrict__ x, float* __restrict__ out,
                          char* __restrict__ ws,
                          const float* __restrict__ W1q, const float* __restrict__ W2q,
                          const float* __restrict__ W1p, const float* __restrict__ W2p,
                          int do_ebuf)
{
    const int blk = blockIdx.x, tid = threadIdx.x;
    if (blk >= NBLK) {
        const int s = blk - NBLK;
        const float* W1 = s ? W1p : W1q;
        const float* W2 = s ? W2p : W2q;
        ushort* f1 = (ushort*)(ws + (s ? OFF_F1P : OFF_F1Q));
        ushort* f2 = (ushort*)(ws + (s ? OFF_F2P : OFF_F2Q));
        for (int idx = tid; idx < 24 * 512; idx += 256) {
            int f = idx >> 9, rem = idx & 511, lane = rem >> 3, j = rem & 7;
            int ks = f >> 3, nt = f & 7;
            int k = ks * 32 + (lane >> 4) * 8 + j, n = nt * 16 + (lane & 15);
            f1[idx] = f2bf(k < DIN ? W1[k * HID + n] : 0.0f);
        }
        for (int idx = tid; idx < 8 * 512; idx += 256) {
            int f = idx >> 9, rem = idx & 511, lane = rem >> 3, j = rem & 7;
            int ks = f >> 1, nt = f & 1;
            int k = ks * 32 + (lane >> 4) * 8 + j, n = nt * 16 + (lane & 15);
            f2[idx] = f2bf(W2[k * DD + n]);
        }
        return;
    }
    const int b = blk >> 6, r = blk & 63;
    const int pt = tid >> 2, j4 = tid & 3;
    const float* src = x + (size_t)(b * NPTS + r * GRID_W + pt) * DIN;
    {
        float* dst = out + (size_t)(b * NPTS + r * GRID_W + pt) * DIN + j4 * 20;
        const float* s4 = src + j4 * 20;
        #pragma unroll
        for (int i = 0; i < 5; ++i)
            *(float4*)(dst + i * 4) = *(const float4*)(s4 + i * 4);
    }
    if (do_ebuf) {
        u64* drow = (u64*)(ws + OFF_EBUF) + ((size_t)((b * 64 + r) * 64) + pt) * 24;
        #pragma unroll
        for (int k = 0; k < 6; ++k) {
            const int m = j4 * 6 + k;
            const int half = m / 12, sub = m % 12;
            const int qR = sub / 3, u = sub - qR * 3;
            const int sbase = qR * 8 + u * 3, cap = qR * 8 + 7;
            const int i1 = (sbase + 1 > cap) ? cap : sbase + 1;
            const int i2 = (sbase + 2 > cap) ? cap : sbase + 2;
            const float* hs = src + (half ? DD : 0);
            u64 pk = (u64)f2bf(hs[sbase]) | ((u64)f2bf(hs[i1]) << 16)
                   | ((u64)f2bf(hs[i2]) << 32);   // tag = 0
            drow[half * 12 + qR * 3 + u] = pk;                    // parity 0
            drow[EB_PAR + half * 12 + qR * 3 + u] = pk | (0xFFFFull << 48); // parity 1: invalid tag
        }
    }
}

struct Acc2 { f32x4 a0, a1; };

// Full F-eval: GEMM1(af0,af1,af2) -> tanh -> sH -> GEMM2 (shared by all paths)
__device__ __forceinline__ Acc2 eval_F(short8 af0, short8 af1, short8 af2,
    const short8* __restrict__ F1, const short8* __restrict__ w2,
    const float* __restrict__ B1, ushort* __restrict__ sH,
    int wv, int lane, int l16, int quad, int q8)
{
    f32x4 acc1[8];
    #pragma unroll
    for (int nt = 0; nt < 8; ++nt) acc1[nt] = (f32x4){0.f, 0.f, 0.f, 0.f};
    #pragma unroll
    for (int nt = 0; nt < 8; ++nt)
        acc1[nt] = __builtin_amdgcn_mfma_f32_16x16x32_bf16(af0, F1[nt * 64 + lane], acc1[nt], 0, 0, 0);
    #pragma unroll
    for (int nt = 0; nt < 8; ++nt)
        acc1[nt] = __builtin_amdgcn_mfma_f32_16x16x32_bf16(af1, F1[(8 + nt) * 64 + lane], acc1[nt], 0, 0, 0);
    #pragma unroll
    for (int nt = 0; nt < 8; ++nt)
        acc1[nt] = __builtin_amdgcn_mfma_f32_16x16x32_bf16(af2, F1[(16 + nt) * 64 + lane], acc1[nt], 0, 0, 0);
    #pragma unroll
    for (int nt = 0; nt < 8; ++nt) {
        const int col = nt * 16 + l16;
        const float bias = B1[col];
        #pragma unroll
        for (int rg = 0; rg < 4; ++rg) {
            const int rowm = wv * 16 + quad * 4 + rg;
            float s = acc1[nt][rg] + bias;
            float e = __expf(2.0f * s);
            float hh = 1.0f - __fdividef(2.0f, e + 1.0f);
            sH[rowm * SH_STRIDE + col] = f2bf(hh);
        }
    }
    Acc2 o;
    o.a0 = (f32x4){0.f, 0.f, 0.f, 0.f};
    o.a1 = (f32x4){0.f, 0.f, 0.f, 0.f};
    #pragma unroll
    for (int ks = 0; ks < 4; ++ks) {
        short8 af = *(const short8*)&sH[(wv * 16 + l16) * SH_STRIDE + ks * 32 + q8];
        o.a0 = __builtin_amdgcn_mfma_f32_16x16x32_bf16(af, w2[ks * 2 + 0], o.a0, 0, 0, 0);
        o.a1 = __builtin_amdgcn_mfma_f32_16x16x32_bf16(af, w2[ks * 2 + 1], o.a1, 0, 0, 0);
    }
    return o;
}

// HALO scheme (r8-proven numerics) + r5-style CHEAP SENTINEL GATE (new):
// the heavy 18-u64 validated receive runs ONCE per step, gated behind a
// 4-lane 8B sentinel poll (p-half sentinels of r±1, r±2 — published last).
// r8's congestion: ungated 144B/lane spins inflated LLC RTs chip-wide.
__global__ __launch_bounds__(256, 2) void sympl_coop(
    float* __restrict__ out, const float* __restrict__ tfinal,
    char* __restrict__ ws,
    const float* __restrict__ b1q, const float* __restrict__ b2q,
    const float* __restrict__ b1p, const float* __restrict__ b2p)
{
    __shared__ __align__(16) float  sQ[64 * SQ_STRIDE];
    __shared__ __align__(16) float  sP[64 * SQ_STRIDE];
    __shared__ __align__(16) ushort sH[64 * SH_STRIDE];
    __shared__ __align__(16) float  sO[4 * 512];
    __shared__ __align__(16) ushort hPm[64 * HB];   // p_recv row r-1 (bf16)
    __shared__ __align__(16) ushort hPp[64 * HB];   // p_recv row r+1
    __shared__ __align__(16) ushort hQm[64 * HB];   // q_recv row r-1
    __shared__ __align__(16) ushort hQp[64 * HB];   // q_recv row r+1
    __shared__ __align__(16) ushort hQNm[64 * HB];  // halo q_new row r-1
    __shared__ __align__(16) ushort hQNp[64 * HB];  // halo q_new row r+1

    u64* eb = (u64*)(ws + OFF_EBUF);
    const int blk = blockIdx.x, tid = threadIdx.x;
    const int b = blk >> 6, r = blk & 63;
    const int wv = tid >> 6, lane = tid & 63;
    const int l16 = lane & 15, quad = lane >> 4, q8 = quad * 8;
    const int c = wv * 16 + l16;
    const int rm = (r + 63) & 63, rp = (r + 1) & 63;
    const int rm2 = (r + 62) & 63, rp2 = (r + 2) & 63;
    const int cm = (c + 63) & 63, cp = (c + 1) & 63;
    const int pt = tid >> 2, sg = (tid & 3) * 8;

    // receive pointers (this lane's quad region of col c): q at +0, p at +12
    const u64* bq_rm = eb + ((size_t)(b * 64 + rm ) * 64 + c) * 24 + quad * 3;
    const u64* bq_rp = eb + ((size_t)(b * 64 + rp ) * 64 + c) * 24 + quad * 3;
    const u64* bp_rm = bq_rm + 12;
    const u64* bp_rp = bq_rp + 12;
    const u64* bp_m2 = eb + ((size_t)(b * 64 + rm2) * 64 + c) * 24 + 12 + quad * 3;
    const u64* bp_p2 = eb + ((size_t)(b * 64 + rp2) * 64 + c) * 24 + 12 + quad * 3;
    // p-half sentinels: last u64 the same-index wave of each source row stores
    // (pt = wv*16+15, slot 23). Published at the END of each producer step.
    const u64* s_pm  = eb + ((size_t)(b * 64 + rm ) * 64 + (wv * 16 + 15)) * 24 + 23;
    const u64* s_pp  = eb + ((size_t)(b * 64 + rp ) * 64 + (wv * 16 + 15)) * 24 + 23;
    const u64* s_pm2 = eb + ((size_t)(b * 64 + rm2) * 64 + (wv * 16 + 15)) * 24 + 23;
    const u64* s_pp2 = eb + ((size_t)(b * 64 + rp2) * 64 + (wv * 16 + 15)) * 24 + 23;
    u64* pub = eb + ((size_t)(b * 64 + r) * 64) * 24;

    // ---- init: own-row q/p -> LDS fp32; xi (own + halo rows) + W2 frags ----
    {
        const float* src = out + (size_t)(b * NPTS + r * GRID_W + pt) * DIN;
        *(float4*)&sQ[pt * SQ_STRIDE + sg]     = *(const float4*)(src + sg);
        *(float4*)&sQ[pt * SQ_STRIDE + sg + 4] = *(const float4*)(src + sg + 4);
        *(float4*)&sP[pt * SQ_STRIDE + sg]     = *(const float4*)(src + DD + sg);
        *(float4*)&sP[pt * SQ_STRIDE + sg + 4] = *(const float4*)(src + DD + sg + 4);
    }
    short8 af2o, af2m, af2p;
    if (quad < 2) {
        const float* pxo = out + (size_t)(b * NPTS + r  * GRID_W + c) * DIN + 2 * DD + q8;
        const float* pxm = out + (size_t)(b * NPTS + rm * GRID_W + c) * DIN + 2 * DD + q8;
        const float* pxp = out + (size_t)(b * NPTS + rp * GRID_W + c) * DIN + 2 * DD + q8;
        af2o = pack8(*(const float4*)pxo, *(const float4*)(pxo + 4));
        af2m = pack8(*(const float4*)pxm, *(const float4*)(pxm + 4));
        af2p = pack8(*(const float4*)pxp, *(const float4*)(pxp + 4));
    } else {
        af2o = (short8)(short)0; af2m = (short8)(short)0; af2p = (short8)(short)0;
    }
    short8 w2q[8], w2p[8];
    {
        const short8* F2q = (const short8*)(ws + OFF_F2Q);
        const short8* F2p = (const short8*)(ws + OFF_F2P);
        #pragma unroll
        for (int i = 0; i < 8; ++i) { w2q[i] = F2q[i * 64 + lane]; w2p[i] = F2p[i * 64 + lane]; }
    }
    const float tf = tfinal[b];
    const short8* F1q = (const short8*)(ws + OFF_F1Q);
    const short8* F1p = (const short8*)(ws + OFF_F1P);
    float* sOw = sO + wv * 512;
    __syncthreads();

    float tq = 0.0f, tp = 0.0f;
    #pragma unroll 1
    for (int k = 0; k < NFULL; ++k) {
        if (tq >= tf) break;                         // batch-uniform exit
        const float dtq = fminf(tf - tq, (k == 0) ? 0.125f : 0.25f);   // > 0
        const float dtp = fminf(fmaxf(tf - tp, 0.0f), 0.25f);
        const uint kk = (uint)k;
        const size_t par_r = (size_t)(k & 1) * EB_PAR;        // receive buffer
        const size_t par_w = (size_t)((k + 1) & 1) * EB_PAR;  // publish buffer

        // ---- CHEAP sentinel gate: 4 lanes x 8B polls (p-half, publ. last) ----
        {
            int spins = 0;
            while (true) {
                bool ok = true;
                if      (lane == 0) ok = ((uint)(ld_sys64(s_pm  + par_r) >> 48) == kk);
                else if (lane == 1) ok = ((uint)(ld_sys64(s_pp  + par_r) >> 48) == kk);
                else if (lane == 2) ok = ((uint)(ld_sys64(s_pm2 + par_r) >> 48) == kk);
                else if (lane == 3) ok = ((uint)(ld_sys64(s_pp2 + par_r) >> 48) == kk);
                if (__all((int)ok)) break;
                if (++spins > SPIN_CAP) break;       // terminate, never hang
                __builtin_amdgcn_s_sleep(1);
            }
        }

        // ---- one-shot validated receive: 18 u64 per lane (retry ~0) ----
        u64 vqm0, vqm1, vqm2, vqp0, vqp1, vqp2;
        u64 vpm0, vpm1, vpm2, vpp0, vpp1, vpp2;
        u64 vm20, vm21, vm22, vp20, vp21, vp22;
        {
            int spins = 0;
            while (true) {
                vqm0 = ld_sys64(bq_rm + par_r);     vqm1 = ld_sys64(bq_rm + par_r + 1); vqm2 = ld_sys64(bq_rm + par_r + 2);
                vqp0 = ld_sys64(bq_rp + par_r);     vqp1 = ld_sys64(bq_rp + par_r + 1); vqp2 = ld_sys64(bq_rp + par_r + 2);
                vpm0 = ld_sys64(bp_rm + par_r);     vpm1 = ld_sys64(bp_rm + par_r + 1); vpm2 = ld_sys64(bp_rm + par_r + 2);
                vpp0 = ld_sys64(bp_rp + par_r);     vpp1 = ld_sys64(bp_rp + par_r + 1); vpp2 = ld_sys64(bp_rp + par_r + 2);
                vm20 = ld_sys64(bp_m2 + par_r);     vm21 = ld_sys64(bp_m2 + par_r + 1); vm22 = ld_sys64(bp_m2 + par_r + 2);
                vp20 = ld_sys64(bp_p2 + par_r);     vp21 = ld_sys64(bp_p2 + par_r + 1); vp22 = ld_sys64(bp_p2 + par_r + 2);
                uint bad = 0;
                bad |= (uint)(vqm0 >> 48) ^ kk; bad |= (uint)(vqm1 >> 48) ^ kk; bad |= (uint)(vqm2 >> 48) ^ kk;
                bad |= (uint)(vqp0 >> 48) ^ kk; bad |= (uint)(vqp1 >> 48) ^ kk; bad |= (uint)(vqp2 >> 48) ^ kk;
                bad |= (uint)(vpm0 >> 48) ^ kk; bad |= (uint)(vpm1 >> 48) ^ kk; bad |= (uint)(vpm2 >> 48) ^ kk;
                bad |= (uint)(vpp0 >> 48) ^ kk; bad |= (uint)(vpp1 >> 48) ^ kk; bad |= (uint)(vpp2 >> 48) ^ kk;
                bad |= (uint)(vm20 >> 48) ^ kk; bad |= (uint)(vm21 >> 48) ^ kk; bad |= (uint)(vm22 >> 48) ^ kk;
                bad |= (uint)(vp20 >> 48) ^ kk; bad |= (uint)(vp21 >> 48) ^ kk; bad |= (uint)(vp22 >> 48) ^ kk;
                if (__all((int)(bad == 0))) break;
                if (++spins > SPIN_CAP) break;       // terminate, never hang
                __builtin_amdgcn_s_sleep(1);
            }
        }
        // stage halo rows to LDS (bf16); p(r±2) stays in registers
        *(short8*)&hQm[c * HB + q8] = u3_to_s8(vqm0, vqm1, vqm2);
        *(short8*)&hQp[c * HB + q8] = u3_to_s8(vqp0, vqp1, vqp2);
        *(short8*)&hPm[c * HB + q8] = u3_to_s8(vpm0, vpm1, vpm2);
        *(short8*)&hPp[c * HB + q8] = u3_to_s8(vpp0, vpp1, vpp2);
        const short8 prm2 = u3_to_s8(vm20, vm21, vm22);
        const short8 prp2 = u3_to_s8(vp20, vp21, vp22);
        __syncthreads();    // halos staged; prev-step sQ/sP stable for all waves

        // ================= PHASE A: q-updates (rows r-1, r, r+1) ============
        float pself[8];
        {
            const float* sc = &sP[c * SQ_STRIDE + q8];
            float4 s0 = *(const float4*)sc, s1 = *(const float4*)(sc + 4);
            pself[0] = s0.x; pself[1] = s0.y; pself[2] = s0.z; pself[3] = s0.w;
            pself[4] = s1.x; pself[5] = s1.y; pself[6] = s1.z; pself[7] = s1.w;
        }
        // ---- halo row r-1: q_new = q_recv + dtq * F(p) ----
        {
            short8 af0 = *(const short8*)&hPm[c * HB + q8];
            short8 ecm = *(const short8*)&hPm[cm * HB + q8];
            short8 ecp = *(const short8*)&hPm[cp * HB + q8];
            union { ushort u[8]; short8 s; } m;
            #pragma unroll
            for (int j = 0; j < 8; ++j)
                m.u[j] = f2bf(0.25f * (bf2f((ushort)ecm[j]) + bf2f((ushort)ecp[j])
                                     + pself[j] + bf2f((ushort)prm2[j])));
            Acc2 A = eval_F(af0, m.s, af2m, F1q, w2q, b1q, sH, wv, lane, l16, quad, q8);
            #pragma unroll
            for (int nt = 0; nt < 2; ++nt) {
                const int col = nt * 16 + l16;
                const float b2v = b2q[col];
                const f32x4 av = nt ? A.a1 : A.a0;
                #pragma unroll
                for (int rg = 0; rg < 4; ++rg)
                    sOw[(quad * 4 + rg) * DD + col] = av[rg] + b2v;
            }
            #pragma unroll
            for (int it = 0; it < 2; ++it) {
                const int slot = lane + it * 64;
                const int lr = slot >> 3, seg = (slot & 7) * 4;
                const int pt_ = wv * 16 + lr;
                const float* po = &sOw[lr * DD + seg];
                u64 old4 = *(const u64*)&hQm[pt_ * HB + seg];
                float o0 = bf2f((ushort)old4)         + dtq * po[0];
                float o1 = bf2f((ushort)(old4 >> 16)) + dtq * po[1];
                float o2 = bf2f((ushort)(old4 >> 32)) + dtq * po[2];
                float o3 = bf2f((ushort)(old4 >> 48)) + dtq * po[3];
                *(u64*)&hQNm[pt_ * HB + seg] =
                    (u64)f2bf(o0) | ((u64)f2bf(o1) << 16) | ((u64)f2bf(o2) << 32) | ((u64)f2bf(o3) << 48);
            }
        }
        // ---- halo row r+1 ----
        {
            short8 af0 = *(const short8*)&hPp[c * HB + q8];
            short8 ecm = *(const short8*)&hPp[cm * HB + q8];
            short8 ecp = *(const short8*)&hPp[cp * HB + q8];
            union { ushort u[8]; short8 s; } m;
            #pragma unroll
            for (int j = 0; j < 8; ++j)
                m.u[j] = f2bf(0.25f * (bf2f((ushort)ecm[j]) + bf2f((ushort)ecp[j])
                                     + pself[j] + bf2f((ushort)prp2[j])));
            Acc2 A = eval_F(af0, m.s, af2p, F1q, w2q, b1q, sH, wv, lane, l16, quad, q8);
            #pragma unroll
            for (int nt = 0; nt < 2; ++nt) {
                const int col = nt * 16 + l16;
                const float b2v = b2q[col];
                const f32x4 av = nt ? A.a1 : A.a0;
                #pragma unroll
                for (int rg = 0; rg < 4; ++rg)
                    sOw[(quad * 4 + rg) * DD + col] = av[rg] + b2v;
            }
            #pragma unroll
            for (int it = 0; it < 2; ++it) {
                const int slot = lane + it * 64;
                const int lr = slot >> 3, seg = (slot & 7) * 4;
                const int pt_ = wv * 16 + lr;
                const float* po = &sOw[lr * DD + seg];
                u64 old4 = *(const u64*)&hQp[pt_ * HB + seg];
                float o0 = bf2f((ushort)old4)         + dtq * po[0];
                float o1 = bf2f((ushort)(old4 >> 16)) + dtq * po[1];
                float o2 = bf2f((ushort)(old4 >> 32)) + dtq * po[2];
                float o3 = bf2f((ushort)(old4 >> 48)) + dtq * po[3];
                *(u64*)&hQNp[pt_ * HB + seg] =
                    (u64)f2bf(o0) | ((u64)f2bf(o1) << 16) | ((u64)f2bf(o2) << 32) | ((u64)f2bf(o3) << 48);
            }
        }
        // ---- own row r: sQ += dtq * F(p); publish q-half tag k+1 ----
        {
            const float* s0p = &sP[c * SQ_STRIDE + q8];
            short8 af0 = pack8(*(const float4*)s0p, *(const float4*)(s0p + 4));
            short8 hm = *(const short8*)&hPm[c * HB + q8];
            short8 hp = *(const short8*)&hPp[c * HB + q8];
            const float* smp = &sP[cm * SQ_STRIDE + q8];
            const float* spp = &sP[cp * SQ_STRIDE + q8];
            float4 l0 = *(const float4*)smp, l1 = *(const float4*)(smp + 4);
            float4 r0 = *(const float4*)spp, r1 = *(const float4*)(spp + 4);
            float lv[8] = { l0.x, l0.y, l0.z, l0.w, l1.x, l1.y, l1.z, l1.w };
            float rv[8] = { r0.x, r0.y, r0.z, r0.w, r1.x, r1.y, r1.z, r1.w };
            union { ushort u[8]; short8 s; } m;
            #pragma unroll
            for (int j = 0; j < 8; ++j)
                m.u[j] = f2bf(0.25f * (bf2f((ushort)hm[j]) + bf2f((ushort)hp[j]) + lv[j] + rv[j]));
            Acc2 A = eval_F(af0, m.s, af2o, F1q, w2q, b1q, sH, wv, lane, l16, quad, q8);
            #pragma unroll
            for (int nt = 0; nt < 2; ++nt) {
                const int col = nt * 16 + l16;
                const float b2v = b2q[col];
                const f32x4 av = nt ? A.a1 : A.a0;
                #pragma unroll
                for (int rg = 0; rg < 4; ++rg)
                    sOw[(quad * 4 + rg) * DD + col] = av[rg] + b2v;
            }
            #pragma unroll
            for (int it = 0; it < 2; ++it) {
                const int slot = lane + it * 64;
                const int lr = slot >> 3, seg = (slot & 7) * 4;
                const int pt_ = wv * 16 + lr;
                const float* po = &sOw[lr * DD + seg];
                float* pl = sQ + pt_ * SQ_STRIDE + seg;
                float4 o = *(const float4*)pl;
                o.x += dtq * po[0]; o.y += dtq * po[1];
                o.z += dtq * po[2]; o.w += dtq * po[3];
                *(float4*)pl = o;
            }
            // publish q-half (tag k+1) into parity buffer par_w
            const u64 tg = ((u64)(ushort)(kk + 1)) << 48;
            #pragma unroll
            for (int t = 0; t < 3; ++t) {
                const int g = t * 64 + lane;
                const int pt_ = g / 12, sub = g - pt_ * 12;
                const int qR = sub / 3, u = sub - qR * 3;
                const int sbase = qR * 8 + u * 3, cap = qR * 8 + 7;
                const int i1 = (sbase + 1 > cap) ? cap : sbase + 1;
                const int i2 = (sbase + 2 > cap) ? cap : sbase + 2;
                const float* pd = sQ + (wv * 16 + pt_) * SQ_STRIDE;
                u64 pk = (u64)f2bf(pd[sbase]) | ((u64)f2bf(pd[i1]) << 16)
                       | ((u64)f2bf(pd[i2]) << 32) | tg;
                st_sys64(pub + par_w + (size_t)(wv * 16 + pt_) * 24 + 0 * 12 + qR * 3 + u, pk);
            }
        }
        __syncthreads();    // sQ(c±1) + hQN visible for phase B

        // ================= PHASE B: p-update (row r) ========================
        if (dtp > 0.0f) {
            const float* s0p = &sQ[c * SQ_STRIDE + q8];
            short8 af0 = pack8(*(const float4*)s0p, *(const float4*)(s0p + 4));
            short8 hm = *(const short8*)&hQNm[c * HB + q8];
            short8 hp = *(const short8*)&hQNp[c * HB + q8];
            const float* smp = &sQ[cm * SQ_STRIDE + q8];
            const float* spp = &sQ[cp * SQ_STRIDE + q8];
            float4 l0 = *(const float4*)smp, l1 = *(const float4*)(smp + 4);
            float4 r0 = *(const float4*)spp, r1 = *(const float4*)(spp + 4);
            float lv[8] = { l0.x, l0.y, l0.z, l0.w, l1.x, l1.y, l1.z, l1.w };
            float rv[8] = { r0.x, r0.y, r0.z, r0.w, r1.x, r1.y, r1.z, r1.w };
            union { ushort u[8]; short8 s; } m;
            #pragma unroll
            for (int j = 0; j < 8; ++j)
                m.u[j] = f2bf(0.25f * (bf2f((ushort)hm[j]) + bf2f((ushort)hp[j]) + lv[j] + rv[j]));
            Acc2 A = eval_F(af0, m.s, af2o, F1p, w2p, b1p, sH, wv, lane, l16, quad, q8);
            #pragma unroll
            for (int nt = 0; nt < 2; ++nt) {
                const int col = nt * 16 + l16;
                const float b2v = b2p[col];
                const f32x4 av = nt ? A.a1 : A.a0;
                #pragma unroll
                for (int rg = 0; rg < 4; ++rg)
                    sOw[(quad * 4 + rg) * DD + col] = av[rg] + b2v;
            }
            #pragma unroll
            for (int it = 0; it < 2; ++it) {
                const int slot = lane + it * 64;
                const int lr = slot >> 3, seg = (slot & 7) * 4;
                const int pt_ = wv * 16 + lr;
                const float* po = &sOw[lr * DD + seg];
                float* pl = sP + pt_ * SQ_STRIDE + seg;
                float4 o = *(const float4*)pl;
                o.x += dtp * po[0]; o.y += dtp * po[1];
                o.z += dtp * po[2]; o.w += dtp * po[3];
                *(float4*)pl = o;
            }
            // publish p-half (tag k+1) into parity buffer par_w
            const u64 tg = ((u64)(ushort)(kk + 1)) << 48;
            #pragma unroll
            for (int t = 0; t < 3; ++t) {
                const int g = t * 64 + lane;
                const int pt_ = g / 12, sub = g - pt_ * 12;
                const int qR = sub / 3, u = sub - qR * 3;
                const int sbase = qR * 8 + u * 3, cap = qR * 8 + 7;
                const int i1 = (sbase + 1 > cap) ? cap : sbase + 1;
                const int i2 = (sbase + 2 > cap) ? cap : sbase + 2;
                const float* pd = sP + (wv * 16 + pt_) * SQ_STRIDE;
                u64 pk = (u64)f2bf(pd[sbase]) | ((u64)f2bf(pd[i1]) << 16)
                       | ((u64)f2bf(pd[i2]) << 32) | tg;
                st_sys64(pub + par_w + (size_t)(wv * 16 + pt_) * 24 + 1 * 12 + qR * 3 + u, pk);
            }
        }
        // dtp == 0: skip publish — all same-batch blocks provably break
        // before waiting on tag k+1 (tf <= 0.25k < 0.125 + 0.25k = their tq).
        tq += (k == 0) ? 0.125f : 0.25f;
        tp += 0.25f;
    }

    // ---- final state -> d_out (pt rows are wave-private: no barrier) ----
    {
        float* dst = out + (size_t)(b * NPTS + r * GRID_W + pt) * DIN;
        *(float4*)(dst + sg)          = *(const float4*)&sQ[pt * SQ_STRIDE + sg];
        *(float4*)(dst + sg + 4)      = *(const float4*)&sQ[pt * SQ_STRIDE + sg + 4];
        *(float4*)(dst + DD + sg)     = *(const float4*)&sP[pt * SQ_STRIDE + sg];
        *(float4*)(dst + DD + sg + 4) = *(const float4*)&sP[pt * SQ_STRIDE + sg + 4];
    }
}

// ---------------- fallback path (proven, global fp32 state) ----------------
__global__ __launch_bounds__(256, 2) void sympl_step(
    float* __restrict__ state, const float* __restrict__ tfinal,
    const char* __restrict__ ws,
    const float* __restrict__ B1, const float* __restrict__ B2,
    int phase, float tcur, float dtmax)
{
    __shared__ __align__(16) ushort sH[64 * SH_STRIDE];
    __shared__ __align__(16) float  sO[4 * 512];
    const int blk = blockIdx.x, tid = threadIdx.x;
    const int wv = tid >> 6, lane = tid & 63;
    const int l16 = lane & 15, quad = lane >> 4, q8 = quad * 8;
    const int b = blk >> 6, r = blk & 63;
    const int c = wv * 16 + l16;

    const float tf = tfinal[b];
    const float dt = fminf(fmaxf(tf - tcur, 0.0f), dtmax);
    if (dt <= 0.0f) return;

    const int srcoff = phase ? 0 : DD;
    const int dstoff = phase ? DD : 0;
    float* bb = state + (size_t)b * NPTS * DIN;
    const float* selfp = bb + (r * GRID_W + c) * DIN;
    const int rm = (r + 63) & 63, rp = (r + 1) & 63;
    const int cm = (c + 63) & 63, cp = (c + 1) & 63;
    short8 af0, af1, af2;
    {
        const float* ps = selfp + srcoff + q8;
        af0 = pack8(*(const float4*)ps, *(const float4*)(ps + 4));
    }
    {
        const float* p0 = bb + (rm * GRID_W + c) * DIN + srcoff + q8;
        const float* p1 = bb + (rp * GRID_W + c) * DIN + srcoff + q8;
        const float* p2 = bb + (r * GRID_W + cm) * DIN + srcoff + q8;
        const float* p3 = bb + (r * GRID_W + cp) * DIN + srcoff + q8;
        float4 a0 = *(const float4*)p0, a1 = *(const float4*)(p0 + 4);
        float4 b0 = *(const float4*)p1, b1v = *(const float4*)(p1 + 4);
        float4 c0 = *(const float4*)p2, c1 = *(const float4*)(p2 + 4);
        float4 d0 = *(const float4*)p3, d1 = *(const float4*)(p3 + 4);
        float4 m0, m1;
        m0.x = 0.25f * (a0.x + b0.x + c0.x + d0.x);
        m0.y = 0.25f * (a0.y + b0.y + c0.y + d0.y);
        m0.z = 0.25f * (a0.z + b0.z + c0.z + d0.z);
        m0.w = 0.25f * (a0.w + b0.w + c0.w + d0.w);
        m1.x = 0.25f * (a1.x + b1v.x + c1.x + d1.x);
        m1.y = 0.25f * (a1.y + b1v.y + c1.y + d1.y);
        m1.z = 0.25f * (a1.z + b1v.z + c1.z + d1.z);
        m1.w = 0.25f * (a1.w + b1v.w + c1.w + d1.w);
        af1 = pack8(m0, m1);
    }
    if (quad < 2) {
        const float* px = selfp + 2 * DD + q8;
        af2 = pack8(*(const float4*)px, *(const float4*)(px + 4));
    } else {
        af2 = (short8)(short)0;
    }
    const short8* F1 = (const short8*)(ws + (phase ? OFF_F1P : OFF_F1Q));
    const short8* F2 = (const short8*)(ws + (phase ? OFF_F2P : OFF_F2Q));
    short8 w2[8];
    #pragma unroll
    for (int i = 0; i < 8; ++i) w2[i] = F2[i * 64 + lane];
    Acc2 A = eval_F(af0, af1, af2, F1, w2, B1, sH, wv, lane, l16, quad, q8);
    float* sOw = sO + wv * 512;
    #pragma unroll
    for (int nt = 0; nt < 2; ++nt) {
        const int col = nt * 16 + l16;
        const float b2v = B2[col];
        const f32x4 av = nt ? A.a1 : A.a0;
        #pragma unroll
        for (int rg = 0; rg < 4; ++rg)
            sOw[(quad * 4 + rg) * DD + col] = av[rg] + b2v;
    }
    #pragma unroll
    for (int it = 0; it < 2; ++it) {
        const int slot = lane + it * 64;
        const int lr = slot >> 3, seg = (slot & 7) * 4;
        float* pd = bb + (r * GRID_W + wv * 16 + lr) * DIN + dstoff + seg;
        const float* po = &sOw[lr * DD + seg];
        float4 o = *(const float4*)pd;
        o.x += dt * po[0]; o.y += dt * po[1];
        o.z += dt * po[2]; o.w += dt * po[3];
        *(float4*)pd = o;
    }
}

extern "C" void kernel_launch(void* const* d_in, const int* in_sizes, int n_in,
                              void* d_out, int out_size, void* d_ws, size_t ws_size,
                              hipStream_t stream)
{
    const float* x   = (const float*)d_in[0];
    const float* tf  = (const float*)d_in[1];
    const float* W1q = (const float*)d_in[2];
    const float* b1q = (const float*)d_in[3];
    const float* W2q = (const float*)d_in[4];
    const float* b2q = (const float*)d_in[5];
    const float* W1p = (const float*)d_in[6];
    const float* b1p = (const float*)d_in[7];
    const float* W2p = (const float*)d_in[8];
    const float* b2p = (const float*)d_in[9];
    float* out = (float*)d_out;
    char* ws = (char*)d_ws;

    const int coop_ok = (ws_size >= WS_NEED) ? 1 : 0;

    // ONE setup launch: x->out copy, tagged-ebuf build (both parities),
    // weight packing.
    setup_all<<<dim3(NBLK + 2), dim3(256), 0, stream>>>(x, out, ws, W1q, W2q,
                                                        W1p, W2p, coop_ok);

    if (coop_ok) {
        sympl_coop<<<dim3(NBLK), dim3(256), 0, stream>>>(
            out, tf, ws, b1q, b2q, b1p, b2p);
    } else {
        // Fallback: 34 regular launches (kernel-boundary coherence).
        float tq = 0.0f, tp = 0.0f;
        for (int h = 0; h < NSTEP; ++h) {
            const int phase = h & 1;
            const float dtmax = phase ? 0.25f : ((h == 0) ? 0.125f : 0.25f);
            const float tcur  = phase ? tp : tq;
            sympl_step<<<dim3(NBLK), dim3(256), 0, stream>>>(
                out, tf, ws, phase ? b1p : b1q, phase ? b2p : b2q,
                phase, tcur, dtmax);
            if (phase) tp += dtmax; else tq += dtmax;
        }
    }
}

// Round 10
// 222.288 us; speedup vs baseline: 2.2894x; 2.2894x over previous
//
#include <hip/hip_runtime.h>
#include <hip/hip_bf16.h>

#define GRID_W 64
#define NPTS   4096
#define BATCH  8
#define DD     32
#define DIN    80
#define HID    128
#define SH_STRIDE 136              // ushort stride (17*16B) -> conflict-free b128
#define SQ_STRIDE 36               // f32 stride for LDS state rows
#define NBLK   512                 // one grid-row per block
#define NSTEP  34                  // max half-steps for tf <= 4.0
#define SPIN_CAP 8192              // timeout => terminate w/ wrong data, never hang
// ws layout: [unused 128KB] | fragments | ebuf (tagged)
#define OFF_F1Q 131072
#define OFF_F2Q (OFF_F1Q + 24*64*16)
#define OFF_F1P (OFF_F2Q + 8*64*16)
#define OFF_F2P (OFF_F1P + 24*64*16)
#define OFF_EBUF 262144
// tagged ebuf: per (b,row,pt): 2 halves x 12 u64. u64 = [3 bf16 | tag].
// half: 4 quad-regions x 3 u64 (quad q: slots 8q..8q+2 | 8q+3..8q+5 | 8q+6,8q+7,dup)
// total = 512 rows * 64 pts * 24 u64 * 8B = 6 MB
#define EB_U64_TOTAL ((size_t)NBLK * 64 * 24)
#define WS_NEED ((size_t)OFF_EBUF + EB_U64_TOTAL * 8)

typedef __attribute__((ext_vector_type(8))) short short8;
typedef __attribute__((ext_vector_type(4))) float f32x4;
typedef unsigned long long u64;

__device__ __forceinline__ ushort f2bf(float v) {
    __hip_bfloat16 h = __float2bfloat16(v);
    return __builtin_bit_cast(ushort, h);
}
__device__ __forceinline__ uint packbf(float a, float b) {
    return (uint)f2bf(a) | ((uint)f2bf(b) << 16);
}
__device__ __forceinline__ short8 pack8(float4 a, float4 b) {
    union { uint u[4]; short8 s; } t;
    t.u[0] = packbf(a.x, a.y); t.u[1] = packbf(a.z, a.w);
    t.u[2] = packbf(b.x, b.y); t.u[3] = packbf(b.z, b.w);
    return t.s;
}
__device__ __forceinline__ float bf2f(ushort u) {
    union { uint i; float f; } t; t.i = ((uint)u) << 16; return t.f;
}

// DEVICE-scope (agent) u64 accessors — THE round-10 experiment.
// r0-r9 used SYSTEM scope, whose coherence point is DRAM (measured: exchange
// traffic shows up as HBM FETCH at 600-960 GB/s). AGENT scope coheres at the
// shared 256MB Infinity Cache: sc1 loads bypass the non-coherent XCD L1/L2
// (so no stale-line hazard, unlike r1-r3's sc0) and are served by the LLC;
// sc1 stores write through to the LLC. Same tag protocol, faster RT.
__device__ __forceinline__ u64 ld_sys64(const u64* p) {
    return __hip_atomic_load(p, __ATOMIC_RELAXED, __HIP_MEMORY_SCOPE_AGENT);
}
__device__ __forceinline__ void st_sys64(u64* p, u64 v) {
    __hip_atomic_store(p, v, __ATOMIC_RELAXED, __HIP_MEMORY_SCOPE_AGENT);
}

// ---- ONE setup kernel: blocks 0..511: copy row x->out, build tagged ebuf
// row (tag=0, both halves); blocks 512/513: pack W1/W2 MFMA fragments.
// Plain stores; kernel-boundary writeback makes all lines LLC-visible.
__global__ void setup_all(const float* __restrict__ x, float* __restrict__ out,
                          char* __restrict__ ws,
                          const float* __restrict__ W1q, const float* __restrict__ W2q,
                          const float* __restrict__ W1p, const float* __restrict__ W2p,
                          int do_ebuf)
{
    const int blk = blockIdx.x, tid = threadIdx.x;
    if (blk >= NBLK) {
        const int s = blk - NBLK;
        const float* W1 = s ? W1p : W1q;
        const float* W2 = s ? W2p : W2q;
        ushort* f1 = (ushort*)(ws + (s ? OFF_F1P : OFF_F1Q));
        ushort* f2 = (ushort*)(ws + (s ? OFF_F2P : OFF_F2Q));
        for (int idx = tid; idx < 24 * 512; idx += 256) {
            int f = idx >> 9, rem = idx & 511, lane = rem >> 3, j = rem & 7;
            int ks = f >> 3, nt = f & 7;
            int k = ks * 32 + (lane >> 4) * 8 + j, n = nt * 16 + (lane & 15);
            f1[idx] = f2bf(k < DIN ? W1[k * HID + n] : 0.0f);
        }
        for (int idx = tid; idx < 8 * 512; idx += 256) {
            int f = idx >> 9, rem = idx & 511, lane = rem >> 3, j = rem & 7;
            int ks = f >> 1, nt = f & 1;
            int k = ks * 32 + (lane >> 4) * 8 + j, n = nt * 16 + (lane & 15);
            f2[idx] = f2bf(W2[k * DD + n]);
        }
        return;
    }
    const int b = blk >> 6, r = blk & 63;
    const int pt = tid >> 2, j4 = tid & 3;
    const float* src = x + (size_t)(b * NPTS + r * GRID_W + pt) * DIN;
    // copy row x -> out: 4 threads/pt, 5 float4 each
    {
        float* dst = out + (size_t)(b * NPTS + r * GRID_W + pt) * DIN + j4 * 20;
        const float* s4 = src + j4 * 20;
        #pragma unroll
        for (int i = 0; i < 5; ++i)
            *(float4*)(dst + i * 4) = *(const float4*)(s4 + i * 4);
    }
    if (do_ebuf) {
        // tagged ebuf row: 24 u64 per pt, 6 per thread, tag = 0
        u64* drow = (u64*)(ws + OFF_EBUF) + ((size_t)((b * 64 + r) * 64) + pt) * 24;
        #pragma unroll
        for (int k = 0; k < 6; ++k) {
            const int m = j4 * 6 + k;            // 0..23
            const int half = m / 12, sub = m % 12;
            const int qR = sub / 3, u = sub - qR * 3;
            const int sbase = qR * 8 + u * 3, cap = qR * 8 + 7;
            const int i1 = (sbase + 1 > cap) ? cap : sbase + 1;
            const int i2 = (sbase + 2 > cap) ? cap : sbase + 2;
            const float* hs = src + (half ? DD : 0);
            u64 pk = (u64)f2bf(hs[sbase]) | ((u64)f2bf(hs[i1]) << 16)
                   | ((u64)f2bf(hs[i2]) << 32);   // tag ushort = 0
            drow[half * 12 + qR * 3 + u] = pk;
        }
    }
}

struct Acc2 { f32x4 a0, a1; };

// (fallback-only) full F-eval helper
__device__ __forceinline__ Acc2 eval_F(short8 af0, short8 af1, short8 af2,
    const short8* __restrict__ F1, const short8* __restrict__ w2,
    const float* __restrict__ B1, ushort* __restrict__ sH,
    int wv, int lane, int l16, int quad, int q8)
{
    f32x4 acc1[8];
    #pragma unroll
    for (int nt = 0; nt < 8; ++nt) acc1[nt] = (f32x4){0.f, 0.f, 0.f, 0.f};
    #pragma unroll
    for (int nt = 0; nt < 8; ++nt)
        acc1[nt] = __builtin_amdgcn_mfma_f32_16x16x32_bf16(af0, F1[nt * 64 + lane], acc1[nt], 0, 0, 0);
    #pragma unroll
    for (int nt = 0; nt < 8; ++nt)
        acc1[nt] = __builtin_amdgcn_mfma_f32_16x16x32_bf16(af1, F1[(8 + nt) * 64 + lane], acc1[nt], 0, 0, 0);
    #pragma unroll
    for (int nt = 0; nt < 8; ++nt)
        acc1[nt] = __builtin_amdgcn_mfma_f32_16x16x32_bf16(af2, F1[(16 + nt) * 64 + lane], acc1[nt], 0, 0, 0);
    #pragma unroll
    for (int nt = 0; nt < 8; ++nt) {
        const int col = nt * 16 + l16;
        const float bias = B1[col];
        #pragma unroll
        for (int rg = 0; rg < 4; ++rg) {
            const int rowm = wv * 16 + quad * 4 + rg;
            float s = acc1[nt][rg] + bias;
            float e = __expf(2.0f * s);
            float hh = 1.0f - __fdividef(2.0f, e + 1.0f);
            sH[rowm * SH_STRIDE + col] = f2bf(hh);
        }
    }
    Acc2 o;
    o.a0 = (f32x4){0.f, 0.f, 0.f, 0.f};
    o.a1 = (f32x4){0.f, 0.f, 0.f, 0.f};
    #pragma unroll
    for (int ks = 0; ks < 4; ++ks) {
        short8 af = *(const short8*)&sH[(wv * 16 + l16) * SH_STRIDE + ks * 32 + q8];
        o.a0 = __builtin_amdgcn_mfma_f32_16x16x32_bf16(af, w2[ks * 2 + 0], o.a0, 0, 0, 0);
        o.a1 = __builtin_amdgcn_mfma_f32_16x16x32_bf16(af, w2[ks * 2 + 1], o.a1, 0, 0, 0);
    }
    return o;
}

// Wave-autonomous rings with SELF-VALIDATING tagged exchange (r6-proven),
// now at AGENT scope (LLC coherence point) instead of SYSTEM (DRAM).
//  * co-residency by capacity: 512 blocks == 256 CU x 2 blocks @ lb(256,2);
//  * protocol is launch-order independent (tags); SPIN_CAP terminates with
//    visibly-wrong results if residency/visibility ever fails — never hangs.
__global__ __launch_bounds__(256, 2) void sympl_coop(
    float* __restrict__ out, const float* __restrict__ tfinal,
    char* __restrict__ ws,
    const float* __restrict__ b1q, const float* __restrict__ b2q,
    const float* __restrict__ b1p, const float* __restrict__ b2p)
{
    __shared__ __align__(16) float  sQ[64 * SQ_STRIDE];
    __shared__ __align__(16) float  sP[64 * SQ_STRIDE];
    __shared__ __align__(16) ushort sH[64 * SH_STRIDE];
    __shared__ __align__(16) float  sO[4 * 512];
    __shared__ uint ldsF[4];

    u64* eb = (u64*)(ws + OFF_EBUF);
    const int blk = blockIdx.x, tid = threadIdx.x;
    const int b = blk >> 6, r = blk & 63;
    const int wv = tid >> 6, lane = tid & 63;
    const int l16 = lane & 15, quad = lane >> 4, q8 = quad * 8;
    const int c = wv * 16 + l16;
    const int rm = (r + 63) & 63, rp = (r + 1) & 63;
    const int cm = (c + 63) & 63, cp = (c + 1) & 63;
    const int pt = tid >> 2, sg = (tid & 3) * 8;

    // neighbor-row chunk pointers (this lane's quad region of col c)
    const u64* prm = eb + ((size_t)(b * 64 + rm) * 64 + c) * 24 + quad * 3;
    const u64* prp = eb + ((size_t)(b * 64 + rp) * 64 + c) * 24 + quad * 3;
    // sentinel = last u64 the neighbor wave stores (pt wv*16+15, qR3,u2)
    const u64* s_rm = eb + ((size_t)(b * 64 + rm) * 64 + (wv * 16 + 15)) * 24 + 11;
    const u64* s_rp = eb + ((size_t)(b * 64 + rp) * 64 + (wv * 16 + 15)) * 24 + 11;
    u64* pub = eb + ((size_t)(b * 64 + r) * 64) * 24;

    // ---- init: own-row q/p -> LDS fp32; xi + W2 fragments -> registers ----
    {
        const float* src = out + (size_t)(b * NPTS + r * GRID_W + pt) * DIN;
        *(float4*)&sQ[pt * SQ_STRIDE + sg]     = *(const float4*)(src + sg);
        *(float4*)&sQ[pt * SQ_STRIDE + sg + 4] = *(const float4*)(src + sg + 4);
        *(float4*)&sP[pt * SQ_STRIDE + sg]     = *(const float4*)(src + DD + sg);
        *(float4*)&sP[pt * SQ_STRIDE + sg + 4] = *(const float4*)(src + DD + sg + 4);
    }
    if (tid < 4) ldsF[tid] = 0;
    short8 af2;
    if (quad < 2) {
        const float* px = out + (size_t)(b * NPTS + r * GRID_W + c) * DIN + 2 * DD + q8;
        af2 = pack8(*(const float4*)px, *(const float4*)(px + 4));
    } else {
        af2 = (short8)(short)0;
    }
    short8 w2q[8], w2p[8];
    {
        const short8* F2q = (const short8*)(ws + OFF_F2Q);
        const short8* F2p = (const short8*)(ws + OFF_F2P);
        #pragma unroll
        for (int i = 0; i < 8; ++i) { w2q[i] = F2q[i * 64 + lane]; w2p[i] = F2p[i * 64 + lane]; }
    }
    const float tf = tfinal[b];
    __syncthreads();                        // LDS state + ldsF visible

    const int wl = (wv + 3) & 3, wr = (wv + 1) & 3;

    float tq = 0.0f, tp = 0.0f;
    #pragma unroll 1
    for (int h = 0; h < NSTEP; ++h) {
        const int phase = h & 1;            // 0: q += dt*F(p); 1: p += dt*F(q)
        const float dtmax = phase ? 0.25f : ((h == 0) ? 0.125f : 0.25f);
        const float tcur  = phase ? tp : tq;
        if (!phase && tq >= tf) break;      // batch-uniform: all rings exit together
        const float dt = fminf(fmaxf(tf - tcur, 0.0f), dtmax);
        const int srcH = phase ^ 1;         // half read (q=0,p=1)
        const int dstH = phase;             // half written
        const float* srcL = phase ? sQ : sP;
        float*       dstL = phase ? sP : sQ;
        const short8* F1 = (const short8*)(ws + (phase ? OFF_F1P : OFF_F1Q));
        const uint hh = (uint)h;

        f32x4 acc1[8];
        if (dt > 0.0f) {                    // pre-wait: self + xi MFMAs
            const float* s0p = srcL + c * SQ_STRIDE + q8;
            float4 a0 = *(const float4*)s0p, a1 = *(const float4*)(s0p + 4);
            short8 af0 = pack8(a0, a1);
            #pragma unroll
            for (int nt = 0; nt < 8; ++nt) acc1[nt] = (f32x4){0.f, 0.f, 0.f, 0.f};
            #pragma unroll
            for (int nt = 0; nt < 8; ++nt)
                acc1[nt] = __builtin_amdgcn_mfma_f32_16x16x32_bf16(af0, F1[nt * 64 + lane], acc1[nt], 0, 0, 0);
            #pragma unroll
            for (int nt = 0; nt < 8; ++nt)
                acc1[nt] = __builtin_amdgcn_mfma_f32_16x16x32_bf16(af2, F1[(16 + nt) * 64 + lane], acc1[nt], 0, 0, 0);
        }

        // ---- wait: row sentinels (tagged data) + column LDS flags ----
        {
            int spins = 0;
            while (true) {
                bool ok = true;
                if (lane == 0)      ok = ((uint)(ld_sys64(s_rm + srcH * 12) >> 48) == hh);
                else if (lane == 1) ok = ((uint)(ld_sys64(s_rp + srcH * 12) >> 48) == hh);
                else if (lane == 2) ok = (__hip_atomic_load(&ldsF[wl], __ATOMIC_RELAXED, __HIP_MEMORY_SCOPE_WORKGROUP) >= hh);
                else if (lane == 3) ok = (__hip_atomic_load(&ldsF[wr], __ATOMIC_RELAXED, __HIP_MEMORY_SCOPE_WORKGROUP) >= hh);
                if (__all((int)ok)) break;
                if (++spins > SPIN_CAP) break;      // terminate, never hang
                __builtin_amdgcn_s_sleep(1);
            }
        }

        if (dt > 0.0f) {                    // block-uniform
            // validated neighbor loads: 6 self-validating u64 per lane
            const u64* pA = prm + srcH * 12;
            const u64* pB = prp + srcH * 12;
            u64 a0, a1, a2, c0, c1, c2;
            int spins = 0;
            while (true) {
                a0 = ld_sys64(pA);     a1 = ld_sys64(pA + 1); a2 = ld_sys64(pA + 2);
                c0 = ld_sys64(pB);     c1 = ld_sys64(pB + 1); c2 = ld_sys64(pB + 2);
                bool ok = ((uint)(a0 >> 48) == hh) & ((uint)(a1 >> 48) == hh)
                        & ((uint)(a2 >> 48) == hh) & ((uint)(c0 >> 48) == hh)
                        & ((uint)(c1 >> 48) == hh) & ((uint)(c2 >> 48) == hh);
                if (__all((int)ok)) break;
                if (++spins > SPIN_CAP) break;      // terminate, never hang
                __builtin_amdgcn_s_sleep(1);
            }

            // column neighbors (LDS) + row neighbors (loads) -> af1
            const float* smp = srcL + cm * SQ_STRIDE + q8;
            const float* spp = srcL + cp * SQ_STRIDE + q8;
            float4 lf0 = *(const float4*)smp, lf1 = *(const float4*)(smp + 4);
            float4 rt0 = *(const float4*)spp, rt1 = *(const float4*)(spp + 4);
            float4 m0, m1;
            m0.x = 0.25f * (bf2f((ushort)a0)         + bf2f((ushort)c0)         + lf0.x + rt0.x);
            m0.y = 0.25f * (bf2f((ushort)(a0 >> 16)) + bf2f((ushort)(c0 >> 16)) + lf0.y + rt0.y);
            m0.z = 0.25f * (bf2f((ushort)(a0 >> 32)) + bf2f((ushort)(c0 >> 32)) + lf0.z + rt0.z);
            m0.w = 0.25f * (bf2f((ushort)a1)         + bf2f((ushort)c1)         + lf0.w + rt0.w);
            m1.x = 0.25f * (bf2f((ushort)(a1 >> 16)) + bf2f((ushort)(c1 >> 16)) + lf1.x + rt1.x);
            m1.y = 0.25f * (bf2f((ushort)(a1 >> 32)) + bf2f((ushort)(c1 >> 32)) + lf1.y + rt1.y);
            m1.z = 0.25f * (bf2f((ushort)a2)         + bf2f((ushort)c2)         + lf1.z + rt1.z);
            m1.w = 0.25f * (bf2f((ushort)(a2 >> 16)) + bf2f((ushort)(c2 >> 16)) + lf1.w + rt1.w);
            short8 af1 = pack8(m0, m1);
            #pragma unroll
            for (int nt = 0; nt < 8; ++nt)
                acc1[nt] = __builtin_amdgcn_mfma_f32_16x16x32_bf16(af1, F1[(8 + nt) * 64 + lane], acc1[nt], 0, 0, 0);

            // tanh -> sH (wave-local rows)
            const float* B1 = phase ? b1p : b1q;
            #pragma unroll
            for (int nt = 0; nt < 8; ++nt) {
                const int col = nt * 16 + l16;
                const float bias = B1[col];
                #pragma unroll
                for (int rg = 0; rg < 4; ++rg) {
                    const int rowm = wv * 16 + quad * 4 + rg;
                    float s = acc1[nt][rg] + bias;
                    float e = __expf(2.0f * s);
                    float hhv = 1.0f - __fdividef(2.0f, e + 1.0f);
                    sH[rowm * SH_STRIDE + col] = f2bf(hhv);
                }
            }
            // GEMM2 (register-resident W2)
            const short8* w2 = phase ? w2p : w2q;
            f32x4 o0 = (f32x4){0.f, 0.f, 0.f, 0.f};
            f32x4 o1 = (f32x4){0.f, 0.f, 0.f, 0.f};
            #pragma unroll
            for (int ks = 0; ks < 4; ++ks) {
                short8 af = *(const short8*)&sH[(wv * 16 + l16) * SH_STRIDE + ks * 32 + q8];
                o0 = __builtin_amdgcn_mfma_f32_16x16x32_bf16(af, w2[ks * 2 + 0], o0, 0, 0, 0);
                o1 = __builtin_amdgcn_mfma_f32_16x16x32_bf16(af, w2[ks * 2 + 1], o1, 0, 0, 0);
            }
            // O -> wave-private sO
            float* sOw = sO + wv * 512;
            const float* B2 = phase ? b2p : b2q;
            #pragma unroll
            for (int nt = 0; nt < 2; ++nt) {
                const int col = nt * 16 + l16;
                const float b2v = B2[col];
                const f32x4 av = nt ? o1 : o0;
                #pragma unroll
                for (int rg = 0; rg < 4; ++rg)
                    sOw[(quad * 4 + rg) * DD + col] = av[rg] + b2v;
            }
            // LDS fp32 RMW (wave-private rows; LDS only — no global stores here)
            #pragma unroll
            for (int it = 0; it < 2; ++it) {
                const int slot = lane + it * 64;   // 128 float4 slots = 16 rows x 8
                const int lr = slot >> 3, seg = (slot & 7) * 4;
                const int pt_ = wv * 16 + lr;
                const float* po = &sOw[lr * DD + seg];
                float* pl = dstL + pt_ * SQ_STRIDE + seg;
                float4 o = *(const float4*)pl;
                o.x += dt * po[0]; o.y += dt * po[1];
                o.z += dt * po[2]; o.w += dt * po[3];
                *(float4*)pl = o;
            }
            // publish: 3 tagged u64 per lane (tag h+1), fire-and-forget
            const u64 tg = ((u64)(ushort)(hh + 1)) << 48;
            #pragma unroll
            for (int t = 0; t < 3; ++t) {
                const int g = t * 64 + lane;            // 0..191
                const int pt_ = g / 12, sub = g - pt_ * 12;
                const int qR = sub / 3, u = sub - qR * 3;
                const int sbase = qR * 8 + u * 3, cap = qR * 8 + 7;
                const int i1 = (sbase + 1 > cap) ? cap : sbase + 1;
                const int i2 = (sbase + 2 > cap) ? cap : sbase + 2;
                const float* pd = dstL + (wv * 16 + pt_) * SQ_STRIDE;
                u64 pk = (u64)f2bf(pd[sbase]) | ((u64)f2bf(pd[i1]) << 16)
                       | ((u64)f2bf(pd[i2]) << 32) | tg;
                st_sys64(pub + (size_t)(wv * 16 + pt_) * 24 + dstH * 12 + qR * 3 + u, pk);
            }
        }
        // column handshake: LDS writes drained, then per-wave flag
        __asm__ volatile("s_waitcnt lgkmcnt(0)" ::: "memory");
        if (lane == 0)
            __hip_atomic_store(&ldsF[wv], (uint)(h + 1), __ATOMIC_RELAXED, __HIP_MEMORY_SCOPE_WORKGROUP);
        if (phase) tp += dtmax; else tq += dtmax;
    }

    // ---- final state -> d_out (pt rows are wave-private: no barrier) ----
    {
        float* dst = out + (size_t)(b * NPTS + r * GRID_W + pt) * DIN;
        *(float4*)(dst + sg)          = *(const float4*)&sQ[pt * SQ_STRIDE + sg];
        *(float4*)(dst + sg + 4)      = *(const float4*)&sQ[pt * SQ_STRIDE + sg + 4];
        *(float4*)(dst + DD + sg)     = *(const float4*)&sP[pt * SQ_STRIDE + sg];
        *(float4*)(dst + DD + sg + 4) = *(const float4*)&sP[pt * SQ_STRIDE + sg + 4];
    }
}

// ---------------- fallback path (proven, global fp32 state) ----------------
__global__ __launch_bounds__(256, 2) void sympl_step(
    float* __restrict__ state, const float* __restrict__ tfinal,
    const char* __restrict__ ws,
    const float* __restrict__ B1, const float* __restrict__ B2,
    int phase, float tcur, float dtmax)
{
    __shared__ __align__(16) ushort sH[64 * SH_STRIDE];
    __shared__ __align__(16) float  sO[4 * 512];
    const int blk = blockIdx.x, tid = threadIdx.x;
    const int wv = tid >> 6, lane = tid & 63;
    const int l16 = lane & 15, quad = lane >> 4, q8 = quad * 8;
    const int b = blk >> 6, r = blk & 63;
    const int c = wv * 16 + l16;

    const float tf = tfinal[b];
    const float dt = fminf(fmaxf(tf - tcur, 0.0f), dtmax);
    if (dt <= 0.0f) return;

    const int srcoff = phase ? 0 : DD;
    const int dstoff = phase ? DD : 0;
    float* bb = state + (size_t)b * NPTS * DIN;
    const float* selfp = bb + (r * GRID_W + c) * DIN;
    const int rm = (r + 63) & 63, rp = (r + 1) & 63;
    const int cm = (c + 63) & 63, cp = (c + 1) & 63;
    short8 af0, af1, af2;
    {
        const float* ps = selfp + srcoff + q8;
        af0 = pack8(*(const float4*)ps, *(const float4*)(ps + 4));
    }
    {
        const float* p0 = bb + (rm * GRID_W + c) * DIN + srcoff + q8;
        const float* p1 = bb + (rp * GRID_W + c) * DIN + srcoff + q8;
        const float* p2 = bb + (r * GRID_W + cm) * DIN + srcoff + q8;
        const float* p3 = bb + (r * GRID_W + cp) * DIN + srcoff + q8;
        float4 a0 = *(const float4*)p0, a1 = *(const float4*)(p0 + 4);
        float4 b0 = *(const float4*)p1, b1v = *(const float4*)(p1 + 4);
        float4 c0 = *(const float4*)p2, c1 = *(const float4*)(p2 + 4);
        float4 d0 = *(const float4*)p3, d1 = *(const float4*)(p3 + 4);
        float4 m0, m1;
        m0.x = 0.25f * (a0.x + b0.x + c0.x + d0.x);
        m0.y = 0.25f * (a0.y + b0.y + c0.y + d0.y);
        m0.z = 0.25f * (a0.z + b0.z + c0.z + d0.z);
        m0.w = 0.25f * (a0.w + b0.w + c0.w + d0.w);
        m1.x = 0.25f * (a1.x + b1v.x + c1.x + d1.x);
        m1.y = 0.25f * (a1.y + b1v.y + c1.y + d1.y);
        m1.z = 0.25f * (a1.z + b1v.z + c1.z + d1.z);
        m1.w = 0.25f * (a1.w + b1v.w + c1.w + d1.w);
        af1 = pack8(m0, m1);
    }
    if (quad < 2) {
        const float* px = selfp + 2 * DD + q8;
        af2 = pack8(*(const float4*)px, *(const float4*)(px + 4));
    } else {
        af2 = (short8)(short)0;
    }
    const short8* F1 = (const short8*)(ws + (phase ? OFF_F1P : OFF_F1Q));
    const short8* F2 = (const short8*)(ws + (phase ? OFF_F2P : OFF_F2Q));
    short8 w2[8];
    #pragma unroll
    for (int i = 0; i < 8; ++i) w2[i] = F2[i * 64 + lane];
    Acc2 A = eval_F(af0, af1, af2, F1, w2, B1, sH, wv, lane, l16, quad, q8);
    float* sOw = sO + wv * 512;
    #pragma unroll
    for (int nt = 0; nt < 2; ++nt) {
        const int col = nt * 16 + l16;
        const float b2v = B2[col];
        const f32x4 av = nt ? A.a1 : A.a0;
        #pragma unroll
        for (int rg = 0; rg < 4; ++rg)
            sOw[(quad * 4 + rg) * DD + col] = av[rg] + b2v;
    }
    #pragma unroll
    for (int it = 0; it < 2; ++it) {
        const int slot = lane + it * 64;
        const int lr = slot >> 3, seg = (slot & 7) * 4;
        float* pd = bb + (r * GRID_W + wv * 16 + lr) * DIN + dstoff + seg;
        const float* po = &sOw[lr * DD + seg];
        float4 o = *(const float4*)pd;
        o.x += dt * po[0]; o.y += dt * po[1];
        o.z += dt * po[2]; o.w += dt * po[3];
        *(float4*)pd = o;
    }
}

extern "C" void kernel_launch(void* const* d_in, const int* in_sizes, int n_in,
                              void* d_out, int out_size, void* d_ws, size_t ws_size,
                              hipStream_t stream)
{
    const float* x   = (const float*)d_in[0];
    const float* tf  = (const float*)d_in[1];
    const float* W1q = (const float*)d_in[2];
    const float* b1q = (const float*)d_in[3];
    const float* W2q = (const float*)d_in[4];
    const float* b2q = (const float*)d_in[5];
    const float* W1p = (const float*)d_in[6];
    const float* b1p = (const float*)d_in[7];
    const float* W2p = (const float*)d_in[8];
    const float* b2p = (const float*)d_in[9];
    float* out = (float*)d_out;
    char* ws = (char*)d_ws;

    const int coop_ok = (ws_size >= WS_NEED) ? 1 : 0;

    // ONE setup launch: x->out copy, tagged-ebuf build, weight packing.
    setup_all<<<dim3(NBLK + 2), dim3(256), 0, stream>>>(x, out, ws, W1q, W2q,
                                                        W1p, W2p, coop_ok);

    if (coop_ok) {
        // Regular launch (r6-proven). Co-residency by capacity
        // (512 blk = 256 CU x 2 @ lb(256,2)); SPIN_CAP guarantees termination.
        sympl_coop<<<dim3(NBLK), dim3(256), 0, stream>>>(
            out, tf, ws, b1q, b2q, b1p, b2p);
    } else {
        // Fallback: 34 regular launches (kernel-boundary coherence).
        float tq = 0.0f, tp = 0.0f;
        for (int h = 0; h < NSTEP; ++h) {
            const int phase = h & 1;
            const float dtmax = phase ? 0.25f : ((h == 0) ? 0.125f : 0.25f);
            const float tcur  = phase ? tp : tq;
            sympl_step<<<dim3(NBLK), dim3(256), 0, stream>>>(
                out, tf, ws, phase ? b1p : b1q, phase ? b2p : b2q,
                phase, tcur, dtmax);
            if (phase) tp += dtmax; else tq += dtmax;
        }
    }
}

// Round 12
// 215.215 us; speedup vs baseline: 2.3647x; 1.0329x over previous
//
#include <hip/hip_runtime.h>
#include <hip/hip_bf16.h>

#define GRID_W 64
#define NPTS   4096
#define BATCH  8
#define DD     32
#define DIN    80
#define HID    128
#define SH_STRIDE 136              // ushort stride (17*16B) -> conflict-free b128
#define SQ_STRIDE 36               // f32 stride for LDS state rows
#define NBLK   512                 // one grid-row per block
#define NSTEP  34                  // max half-steps for tf <= 4.0
#define SPIN_CAP 8192              // timeout => terminate w/ wrong data, never hang
// ws layout: [unused 128KB] | fragments | ebuf (tagged)
#define OFF_F1Q 131072
#define OFF_F2Q (OFF_F1Q + 24*64*16)
#define OFF_F1P (OFF_F2Q + 8*64*16)
#define OFF_F2P (OFF_F1P + 24*64*16)
#define OFF_EBUF 262144
// tagged ebuf: per (b,row,pt): 2 halves x 12 u64. u64 = [3 bf16 | tag].
// half: 4 quad-regions x 3 u64 (quad q: slots 8q..8q+2 | 8q+3..8q+5 | 8q+6,8q+7,dup)
// total = 512 rows * 64 pts * 24 u64 * 8B = 6 MB
#define EB_U64_TOTAL ((size_t)NBLK * 64 * 24)
#define WS_NEED ((size_t)OFF_EBUF + EB_U64_TOTAL * 8)

typedef __attribute__((ext_vector_type(8))) short short8;
typedef __attribute__((ext_vector_type(4))) float f32x4;
typedef unsigned long long u64;

__device__ __forceinline__ ushort f2bf(float v) {
    __hip_bfloat16 h = __float2bfloat16(v);
    return __builtin_bit_cast(ushort, h);
}
__device__ __forceinline__ uint packbf(float a, float b) {
    return (uint)f2bf(a) | ((uint)f2bf(b) << 16);
}
__device__ __forceinline__ short8 pack8(float4 a, float4 b) {
    union { uint u[4]; short8 s; } t;
    t.u[0] = packbf(a.x, a.y); t.u[1] = packbf(a.z, a.w);
    t.u[2] = packbf(b.x, b.y); t.u[3] = packbf(b.z, b.w);
    return t.s;
}
__device__ __forceinline__ float bf2f(ushort u) {
    union { uint i; float f; } t; t.i = ((uint)u) << 16; return t.f;
}

// Agent-scope u64 accessors (r10: measured identical to system scope on this
// protocol; LLC is the coherence point either way for cross-XCD exchange).
__device__ __forceinline__ u64 ld_sys64(const u64* p) {
    return __hip_atomic_load(p, __ATOMIC_RELAXED, __HIP_MEMORY_SCOPE_AGENT);
}
__device__ __forceinline__ void st_sys64(u64* p, u64 v) {
    __hip_atomic_store(p, v, __ATOMIC_RELAXED, __HIP_MEMORY_SCOPE_AGENT);
}

// ---- ONE setup kernel (no x->out copy; LDS-staged ebuf build).
// Blocks 0..511: build tagged ebuf row (tag=0) from x via coalesced float4
// reads + LDS scalars. Blocks 512/513: pack W1/W2 MFMA fragments.
// Plain stores; kernel-boundary writeback makes all lines LLC-visible.
__global__ void setup_all(const float* __restrict__ x,
                          char* __restrict__ ws,
                          const float* __restrict__ W1q, const float* __restrict__ W2q,
                          const float* __restrict__ W1p, const float* __restrict__ W2p,
                          int do_ebuf)
{
    __shared__ float st[64 * 64];   // [pt][0..31 q | 32..63 p]
    const int blk = blockIdx.x, tid = threadIdx.x;
    if (blk >= NBLK) {
        const int s = blk - NBLK;
        const float* W1 = s ? W1p : W1q;
        const float* W2 = s ? W2p : W2q;
        ushort* f1 = (ushort*)(ws + (s ? OFF_F1P : OFF_F1Q));
        ushort* f2 = (ushort*)(ws + (s ? OFF_F2P : OFF_F2Q));
        for (int idx = tid; idx < 24 * 512; idx += 256) {
            int f = idx >> 9, rem = idx & 511, lane = rem >> 3, j = rem & 7;
            int ks = f >> 3, nt = f & 7;
            int k = ks * 32 + (lane >> 4) * 8 + j, n = nt * 16 + (lane & 15);
            f1[idx] = f2bf(k < DIN ? W1[k * HID + n] : 0.0f);
        }
        for (int idx = tid; idx < 8 * 512; idx += 256) {
            int f = idx >> 9, rem = idx & 511, lane = rem >> 3, j = rem & 7;
            int ks = f >> 1, nt = f & 1;
            int k = ks * 32 + (lane >> 4) * 8 + j, n = nt * 16 + (lane & 15);
            f2[idx] = f2bf(W2[k * DD + n]);
        }
        return;
    }
    if (!do_ebuf) return;
    const int b = blk >> 6, r = blk & 63;
    const int pt = tid >> 2, j4 = tid & 3, sg = j4 * 8;
    // coalesced q/p -> LDS
    {
        const float* src = x + (size_t)(b * NPTS + r * GRID_W + pt) * DIN;
        *(float4*)&st[pt * 64 + sg]          = *(const float4*)(src + sg);
        *(float4*)&st[pt * 64 + sg + 4]      = *(const float4*)(src + sg + 4);
        *(float4*)&st[pt * 64 + 32 + sg]     = *(const float4*)(src + DD + sg);
        *(float4*)&st[pt * 64 + 32 + sg + 4] = *(const float4*)(src + DD + sg + 4);
    }
    __syncthreads();
    // tagged ebuf: 6 u64 per thread, contiguous stores per pt, tag = 0
    u64* drow = (u64*)(ws + OFF_EBUF) + ((size_t)((b * 64 + r) * 64) + pt) * 24;
    const float* hs0 = &st[pt * 64];
    #pragma unroll
    for (int k = 0; k < 6; ++k) {
        const int m = j4 * 6 + k;            // 0..23 (== drow index)
        const int half = m / 12, sub = m % 12;
        const int qR = sub / 3, u = sub - qR * 3;
        const int sbase = qR * 8 + u * 3, cap = qR * 8 + 7;
        const int i1 = (sbase + 1 > cap) ? cap : sbase + 1;
        const int i2 = (sbase + 2 > cap) ? cap : sbase + 2;
        const float* hs = hs0 + (half ? 32 : 0);
        u64 pk = (u64)f2bf(hs[sbase]) | ((u64)f2bf(hs[i1]) << 16)
               | ((u64)f2bf(hs[i2]) << 32);   // tag ushort = 0
        drow[m] = pk;
    }
}

struct Acc2 { f32x4 a0, a1; };

// (fallback-only) full F-eval helper
__device__ __forceinline__ Acc2 eval_F(short8 af0, short8 af1, short8 af2,
    const short8* __restrict__ F1, const short8* __restrict__ w2,
    const float* __restrict__ B1, ushort* __restrict__ sH,
    int wv, int lane, int l16, int quad, int q8)
{
    f32x4 acc1[8];
    #pragma unroll
    for (int nt = 0; nt < 8; ++nt) acc1[nt] = (f32x4){0.f, 0.f, 0.f, 0.f};
    #pragma unroll
    for (int nt = 0; nt < 8; ++nt)
        acc1[nt] = __builtin_amdgcn_mfma_f32_16x16x32_bf16(af0, F1[nt * 64 + lane], acc1[nt], 0, 0, 0);
    #pragma unroll
    for (int nt = 0; nt < 8; ++nt)
        acc1[nt] = __builtin_amdgcn_mfma_f32_16x16x32_bf16(af1, F1[(8 + nt) * 64 + lane], acc1[nt], 0, 0, 0);
    #pragma unroll
    for (int nt = 0; nt < 8; ++nt)
        acc1[nt] = __builtin_amdgcn_mfma_f32_16x16x32_bf16(af2, F1[(16 + nt) * 64 + lane], acc1[nt], 0, 0, 0);
    #pragma unroll
    for (int nt = 0; nt < 8; ++nt) {
        const int col = nt * 16 + l16;
        const float bias = B1[col];
        #pragma unroll
        for (int rg = 0; rg < 4; ++rg) {
            const int rowm = wv * 16 + quad * 4 + rg;
            float s = acc1[nt][rg] + bias;
            float e = __expf(2.0f * s);
            float hh = 1.0f - __fdividef(2.0f, e + 1.0f);
            sH[rowm * SH_STRIDE + col] = f2bf(hh);
        }
    }
    Acc2 o;
    o.a0 = (f32x4){0.f, 0.f, 0.f, 0.f};
    o.a1 = (f32x4){0.f, 0.f, 0.f, 0.f};
    #pragma unroll
    for (int ks = 0; ks < 4; ++ks) {
        short8 af = *(const short8*)&sH[(wv * 16 + l16) * SH_STRIDE + ks * 32 + q8];
        o.a0 = __builtin_amdgcn_mfma_f32_16x16x32_bf16(af, w2[ks * 2 + 0], o.a0, 0, 0, 0);
        o.a1 = __builtin_amdgcn_mfma_f32_16x16x32_bf16(af, w2[ks * 2 + 1], o.a1, 0, 0, 0);
    }
    return o;
}

// Wave-autonomous rings with SELF-VALIDATING tagged exchange (r6/r10-proven).
// Reads initial state + xi directly from x (no out pre-population);
// final write-out emits q, p AND xi (fp32 copy from x). Loop untouched.
__global__ __launch_bounds__(256, 2) void sympl_coop(
    float* __restrict__ out, const float* __restrict__ x,
    const float* __restrict__ tfinal,
    char* __restrict__ ws,
    const float* __restrict__ b1q, const float* __restrict__ b2q,
    const float* __restrict__ b1p, const float* __restrict__ b2p)
{
    __shared__ __align__(16) float  sQ[64 * SQ_STRIDE];
    __shared__ __align__(16) float  sP[64 * SQ_STRIDE];
    __shared__ __align__(16) ushort sH[64 * SH_STRIDE];
    __shared__ __align__(16) float  sO[4 * 512];
    __shared__ uint ldsF[4];

    u64* eb = (u64*)(ws + OFF_EBUF);
    const int blk = blockIdx.x, tid = threadIdx.x;
    const int b = blk >> 6, r = blk & 63;
    const int wv = tid >> 6, lane = tid & 63;
    const int l16 = lane & 15, quad = lane >> 4, q8 = quad * 8;
    const int c = wv * 16 + l16;
    const int rm = (r + 63) & 63, rp = (r + 1) & 63;
    const int cm = (c + 63) & 63, cp = (c + 1) & 63;
    const int pt = tid >> 2, sg = (tid & 3) * 8;

    // neighbor-row chunk pointers (this lane's quad region of col c)
    const u64* prm = eb + ((size_t)(b * 64 + rm) * 64 + c) * 24 + quad * 3;
    const u64* prp = eb + ((size_t)(b * 64 + rp) * 64 + c) * 24 + quad * 3;
    // sentinel = last u64 the neighbor wave stores (pt wv*16+15, qR3,u2)
    const u64* s_rm = eb + ((size_t)(b * 64 + rm) * 64 + (wv * 16 + 15)) * 24 + 11;
    const u64* s_rp = eb + ((size_t)(b * 64 + rp) * 64 + (wv * 16 + 15)) * 24 + 11;
    u64* pub = eb + ((size_t)(b * 64 + r) * 64) * 24;

    // ---- init: own-row q/p from x -> LDS fp32; xi + W2 fragments -> regs ----
    {
        const float* src = x + (size_t)(b * NPTS + r * GRID_W + pt) * DIN;
        *(float4*)&sQ[pt * SQ_STRIDE + sg]     = *(const float4*)(src + sg);
        *(float4*)&sQ[pt * SQ_STRIDE + sg + 4] = *(const float4*)(src + sg + 4);
        *(float4*)&sP[pt * SQ_STRIDE + sg]     = *(const float4*)(src + DD + sg);
        *(float4*)&sP[pt * SQ_STRIDE + sg + 4] = *(const float4*)(src + DD + sg + 4);
    }
    if (tid < 4) ldsF[tid] = 0;
    short8 af2;
    if (quad < 2) {
        const float* px = x + (size_t)(b * NPTS + r * GRID_W + c) * DIN + 2 * DD + q8;
        af2 = pack8(*(const float4*)px, *(const float4*)(px + 4));
    } else {
        af2 = (short8)(short)0;
    }
    short8 w2q[8], w2p[8];
    {
        const short8* F2q = (const short8*)(ws + OFF_F2Q);
        const short8* F2p = (const short8*)(ws + OFF_F2P);
        #pragma unroll
        for (int i = 0; i < 8; ++i) { w2q[i] = F2q[i * 64 + lane]; w2p[i] = F2p[i * 64 + lane]; }
    }
    const float tf = tfinal[b];
    __syncthreads();                        // LDS state + ldsF visible

    const int wl = (wv + 3) & 3, wr = (wv + 1) & 3;

    float tq = 0.0f, tp = 0.0f;
    #pragma unroll 1
    for (int h = 0; h < NSTEP; ++h) {
        const int phase = h & 1;            // 0: q += dt*F(p); 1: p += dt*F(q)
        const float dtmax = phase ? 0.25f : ((h == 0) ? 0.125f : 0.25f);
        const float tcur  = phase ? tp : tq;
        if (!phase && tq >= tf) break;      // batch-uniform: all rings exit together
        const float dt = fminf(fmaxf(tf - tcur, 0.0f), dtmax);
        const int srcH = phase ^ 1;         // half read (q=0,p=1)
        const int dstH = phase;             // half written
        const float* srcL = phase ? sQ : sP;
        float*       dstL = phase ? sP : sQ;
        const short8* F1 = (const short8*)(ws + (phase ? OFF_F1P : OFF_F1Q));
        const uint hh = (uint)h;

        f32x4 acc1[8];
        if (dt > 0.0f) {                    // pre-wait: self + xi MFMAs
            const float* s0p = srcL + c * SQ_STRIDE + q8;
            float4 a0 = *(const float4*)s0p, a1 = *(const float4*)(s0p + 4);
            short8 af0 = pack8(a0, a1);
            #pragma unroll
            for (int nt = 0; nt < 8; ++nt) acc1[nt] = (f32x4){0.f, 0.f, 0.f, 0.f};
            #pragma unroll
            for (int nt = 0; nt < 8; ++nt)
                acc1[nt] = __builtin_amdgcn_mfma_f32_16x16x32_bf16(af0, F1[nt * 64 + lane], acc1[nt], 0, 0, 0);
            #pragma unroll
            for (int nt = 0; nt < 8; ++nt)
                acc1[nt] = __builtin_amdgcn_mfma_f32_16x16x32_bf16(af2, F1[(16 + nt) * 64 + lane], acc1[nt], 0, 0, 0);
        }

        // ---- wait: row sentinels (tagged data) + column LDS flags ----
        {
            int spins = 0;
            while (true) {
                bool ok = true;
                if (lane == 0)      ok = ((uint)(ld_sys64(s_rm + srcH * 12) >> 48) == hh);
                else if (lane == 1) ok = ((uint)(ld_sys64(s_rp + srcH * 12) >> 48) == hh);
                else if (lane == 2) ok = (__hip_atomic_load(&ldsF[wl], __ATOMIC_RELAXED, __HIP_MEMORY_SCOPE_WORKGROUP) >= hh);
                else if (lane == 3) ok = (__hip_atomic_load(&ldsF[wr], __ATOMIC_RELAXED, __HIP_MEMORY_SCOPE_WORKGROUP) >= hh);
                if (__all((int)ok)) break;
                if (++spins > SPIN_CAP) break;      // terminate, never hang
                __builtin_amdgcn_s_sleep(1);
            }
        }

        if (dt > 0.0f) {                    // block-uniform
            // validated neighbor loads: 6 self-validating u64 per lane
            const u64* pA = prm + srcH * 12;
            const u64* pB = prp + srcH * 12;
            u64 a0, a1, a2, c0, c1, c2;
            int spins = 0;
            while (true) {
                a0 = ld_sys64(pA);     a1 = ld_sys64(pA + 1); a2 = ld_sys64(pA + 2);
                c0 = ld_sys64(pB);     c1 = ld_sys64(pB + 1); c2 = ld_sys64(pB + 2);
                bool ok = ((uint)(a0 >> 48) == hh) & ((uint)(a1 >> 48) == hh)
                        & ((uint)(a2 >> 48) == hh) & ((uint)(c0 >> 48) == hh)
                        & ((uint)(c1 >> 48) == hh) & ((uint)(c2 >> 48) == hh);
                if (__all((int)ok)) break;
                if (++spins > SPIN_CAP) break;      // terminate, never hang
                __builtin_amdgcn_s_sleep(1);
            }

            // column neighbors (LDS) + row neighbors (loads) -> af1
            const float* smp = srcL + cm * SQ_STRIDE + q8;
            const float* spp = srcL + cp * SQ_STRIDE + q8;
            float4 lf0 = *(const float4*)smp, lf1 = *(const float4*)(smp + 4);
            float4 rt0 = *(const float4*)spp, rt1 = *(const float4*)(spp + 4);
            float4 m0, m1;
            m0.x = 0.25f * (bf2f((ushort)a0)         + bf2f((ushort)c0)         + lf0.x + rt0.x);
            m0.y = 0.25f * (bf2f((ushort)(a0 >> 16)) + bf2f((ushort)(c0 >> 16)) + lf0.y + rt0.y);
            m0.z = 0.25f * (bf2f((ushort)(a0 >> 32)) + bf2f((ushort)(c0 >> 32)) + lf0.z + rt0.z);
            m0.w = 0.25f * (bf2f((ushort)a1)         + bf2f((ushort)c1)         + lf0.w + rt0.w);
            m1.x = 0.25f * (bf2f((ushort)(a1 >> 16)) + bf2f((ushort)(c1 >> 16)) + lf1.x + rt1.x);
            m1.y = 0.25f * (bf2f((ushort)(a1 >> 32)) + bf2f((ushort)(c1 >> 32)) + lf1.y + rt1.y);
            m1.z = 0.25f * (bf2f((ushort)a2)         + bf2f((ushort)c2)         + lf1.z + rt1.z);
            m1.w = 0.25f * (bf2f((ushort)(a2 >> 16)) + bf2f((ushort)(c2 >> 16)) + lf1.w + rt1.w);
            short8 af1 = pack8(m0, m1);
            #pragma unroll
            for (int nt = 0; nt < 8; ++nt)
                acc1[nt] = __builtin_amdgcn_mfma_f32_16x16x32_bf16(af1, F1[(8 + nt) * 64 + lane], acc1[nt], 0, 0, 0);

            // tanh -> sH (wave-local rows)
            const float* B1 = phase ? b1p : b1q;
            #pragma unroll
            for (int nt = 0; nt < 8; ++nt) {
                const int col = nt * 16 + l16;
                const float bias = B1[col];
                #pragma unroll
                for (int rg = 0; rg < 4; ++rg) {
                    const int rowm = wv * 16 + quad * 4 + rg;
                    float s = acc1[nt][rg] + bias;
                    float e = __expf(2.0f * s);
                    float hhv = 1.0f - __fdividef(2.0f, e + 1.0f);
                    sH[rowm * SH_STRIDE + col] = f2bf(hhv);
                }
            }
            // GEMM2 (register-resident W2)
            const short8* w2 = phase ? w2p : w2q;
            f32x4 o0 = (f32x4){0.f, 0.f, 0.f, 0.f};
            f32x4 o1 = (f32x4){0.f, 0.f, 0.f, 0.f};
            #pragma unroll
            for (int ks = 0; ks < 4; ++ks) {
                short8 af = *(const short8*)&sH[(wv * 16 + l16) * SH_STRIDE + ks * 32 + q8];
                o0 = __builtin_amdgcn_mfma_f32_16x16x32_bf16(af, w2[ks * 2 + 0], o0, 0, 0, 0);
                o1 = __builtin_amdgcn_mfma_f32_16x16x32_bf16(af, w2[ks * 2 + 1], o1, 0, 0, 0);
            }
            // O -> wave-private sO
            float* sOw = sO + wv * 512;
            const float* B2 = phase ? b2p : b2q;
            #pragma unroll
            for (int nt = 0; nt < 2; ++nt) {
                const int col = nt * 16 + l16;
                const float b2v = B2[col];
                const f32x4 av = nt ? o1 : o0;
                #pragma unroll
                for (int rg = 0; rg < 4; ++rg)
                    sOw[(quad * 4 + rg) * DD + col] = av[rg] + b2v;
            }
            // LDS fp32 RMW (wave-private rows; LDS only — no global stores here)
            #pragma unroll
            for (int it = 0; it < 2; ++it) {
                const int slot = lane + it * 64;   // 128 float4 slots = 16 rows x 8
                const int lr = slot >> 3, seg = (slot & 7) * 4;
                const int pt_ = wv * 16 + lr;
                const float* po = &sOw[lr * DD + seg];
                float* pl = dstL + pt_ * SQ_STRIDE + seg;
                float4 o = *(const float4*)pl;
                o.x += dt * po[0]; o.y += dt * po[1];
                o.z += dt * po[2]; o.w += dt * po[3];
                *(float4*)pl = o;
            }
            // publish: 3 tagged u64 per lane (tag h+1), fire-and-forget
            const u64 tg = ((u64)(ushort)(hh + 1)) << 48;
            #pragma unroll
            for (int t = 0; t < 3; ++t) {
                const int g = t * 64 + lane;            // 0..191
                const int pt_ = g / 12, sub = g - pt_ * 12;
                const int qR = sub / 3, u = sub - qR * 3;
                const int sbase = qR * 8 + u * 3, cap = qR * 8 + 7;
                const int i1 = (sbase + 1 > cap) ? cap : sbase + 1;
                const int i2 = (sbase + 2 > cap) ? cap : sbase + 2;
                const float* pd = dstL + (wv * 16 + pt_) * SQ_STRIDE;
                u64 pk = (u64)f2bf(pd[sbase]) | ((u64)f2bf(pd[i1]) << 16)
                       | ((u64)f2bf(pd[i2]) << 32) | tg;
                st_sys64(pub + (size_t)(wv * 16 + pt_) * 24 + dstH * 12 + qR * 3 + u, pk);
            }
        }
        // column handshake: LDS writes drained, then per-wave flag
        __asm__ volatile("s_waitcnt lgkmcnt(0)" ::: "memory");
        if (lane == 0)
            __hip_atomic_store(&ldsF[wv], (uint)(h + 1), __ATOMIC_RELAXED, __HIP_MEMORY_SCOPE_WORKGROUP);
        if (phase) tp += dtmax; else tq += dtmax;
    }

    // ---- final state -> d_out: q, p from LDS; xi copied fp32 from x ----
    {
        float* dst = out + (size_t)(b * NPTS + r * GRID_W + pt) * DIN;
        const float* sx = x + (size_t)(b * NPTS + r * GRID_W + pt) * DIN;
        *(float4*)(dst + sg)          = *(const float4*)&sQ[pt * SQ_STRIDE + sg];
        *(float4*)(dst + sg + 4)      = *(const float4*)&sQ[pt * SQ_STRIDE + sg + 4];
        *(float4*)(dst + DD + sg)     = *(const float4*)&sP[pt * SQ_STRIDE + sg];
        *(float4*)(dst + DD + sg + 4) = *(const float4*)&sP[pt * SQ_STRIDE + sg + 4];
        const int xo = 2 * DD + (tid & 3) * 4;   // 16 xi floats / 4 threads
        *(float4*)(dst + xo) = *(const float4*)(sx + xo);
    }
}

// ---------------- fallback path (proven, global fp32 state) ----------------
__global__ __launch_bounds__(256, 2) void sympl_step(
    float* __restrict__ state, const float* __restrict__ tfinal,
    const char* __restrict__ ws,
    const float* __restrict__ B1, const float* __restrict__ B2,
    int phase, float tcur, float dtmax)
{
    __shared__ __align__(16) ushort sH[64 * SH_STRIDE];
    __shared__ __align__(16) float  sO[4 * 512];
    const int blk = blockIdx.x, tid = threadIdx.x;
    const int wv = tid >> 6, lane = tid & 63;
    const int l16 = lane & 15, quad = lane >> 4, q8 = quad * 8;
    const int b = blk >> 6, r = blk & 63;
    const int c = wv * 16 + l16;

    const float tf = tfinal[b];
    const float dt = fminf(fmaxf(tf - tcur, 0.0f), dtmax);
    if (dt <= 0.0f) return;

    const int srcoff = phase ? 0 : DD;
    const int dstoff = phase ? DD : 0;
    float* bb = state + (size_t)b * NPTS * DIN;
    const float* selfp = bb + (r * GRID_W + c) * DIN;
    const int rm = (r + 63) & 63, rp = (r + 1) & 63;
    const int cm = (c + 63) & 63, cp = (c + 1) & 63;
    short8 af0, af1, af2;
    {
        const float* ps = selfp + srcoff + q8;
        af0 = pack8(*(const float4*)ps, *(const float4*)(ps + 4));
    }
    {
        const float* p0 = bb + (rm * GRID_W + c) * DIN + srcoff + q8;
        const float* p1 = bb + (rp * GRID_W + c) * DIN + srcoff + q8;
        const float* p2 = bb + (r * GRID_W + cm) * DIN + srcoff + q8;
        const float* p3 = bb + (r * GRID_W + cp) * DIN + srcoff + q8;
        float4 a0 = *(const float4*)p0, a1 = *(const float4*)(p0 + 4);
        float4 b0 = *(const float4*)p1, b1v = *(const float4*)(p1 + 4);
        float4 c0 = *(const float4*)p2, c1 = *(const float4*)(p2 + 4);
        float4 d0 = *(const float4*)p3, d1 = *(const float4*)(p3 + 4);
        float4 m0, m1;
        m0.x = 0.25f * (a0.x + b0.x + c0.x + d0.x);
        m0.y = 0.25f * (a0.y + b0.y + c0.y + d0.y);
        m0.z = 0.25f * (a0.z + b0.z + c0.z + d0.z);
        m0.w = 0.25f * (a0.w + b0.w + c0.w + d0.w);
        m1.x = 0.25f * (a1.x + b1v.x + c1.x + d1.x);
        m1.y = 0.25f * (a1.y + b1v.y + c1.y + d1.y);
        m1.z = 0.25f * (a1.z + b1v.z + c1.z + d1.z);
        m1.w = 0.25f * (a1.w + b1v.w + c1.w + d1.w);
        af1 = pack8(m0, m1);
    }
    if (quad < 2) {
        const float* px = selfp + 2 * DD + q8;
        af2 = pack8(*(const float4*)px, *(const float4*)(px + 4));
    } else {
        af2 = (short8)(short)0;
    }
    const short8* F1 = (const short8*)(ws + (phase ? OFF_F1P : OFF_F1Q));
    const short8* F2 = (const short8*)(ws + (phase ? OFF_F2P : OFF_F2Q));
    short8 w2[8];
    #pragma unroll
    for (int i = 0; i < 8; ++i) w2[i] = F2[i * 64 + lane];
    Acc2 A = eval_F(af0, af1, af2, F1, w2, B1, sH, wv, lane, l16, quad, q8);
    float* sOw = sO + wv * 512;
    #pragma unroll
    for (int nt = 0; nt < 2; ++nt) {
        const int col = nt * 16 + l16;
        const float b2v = B2[col];
        const f32x4 av = nt ? A.a1 : A.a0;
        #pragma unroll
        for (int rg = 0; rg < 4; ++rg)
            sOw[(quad * 4 + rg) * DD + col] = av[rg] + b2v;
    }
    #pragma unroll
    for (int it = 0; it < 2; ++it) {
        const int slot = lane + it * 64;
        const int lr = slot >> 3, seg = (slot & 7) * 4;
        float* pd = bb + (r * GRID_W + wv * 16 + lr) * DIN + dstoff + seg;
        const float* po = &sOw[lr * DD + seg];
        float4 o = *(const float4*)pd;
        o.x += dt * po[0]; o.y += dt * po[1];
        o.z += dt * po[2]; o.w += dt * po[3];
        *(float4*)pd = o;
    }
}

extern "C" void kernel_launch(void* const* d_in, const int* in_sizes, int n_in,
                              void* d_out, int out_size, void* d_ws, size_t ws_size,
                              hipStream_t stream)
{
    const float* x   = (const float*)d_in[0];
    const float* tf  = (const float*)d_in[1];
    const float* W1q = (const float*)d_in[2];
    const float* b1q = (const float*)d_in[3];
    const float* W2q = (const float*)d_in[4];
    const float* b2q = (const float*)d_in[5];
    const float* W1p = (const float*)d_in[6];
    const float* b1p = (const float*)d_in[7];
    const float* W2p = (const float*)d_in[8];
    const float* b2p = (const float*)d_in[9];
    float* out = (float*)d_out;
    char* ws = (char*)d_ws;

    const int coop_ok = (ws_size >= WS_NEED) ? 1 : 0;

    // ONE setup launch: tagged-ebuf build + weight packing (no x->out copy).
    setup_all<<<dim3(NBLK + 2), dim3(256), 0, stream>>>(x, ws, W1q, W2q,
                                                        W1p, W2p, coop_ok);

    if (coop_ok) {
        sympl_coop<<<dim3(NBLK), dim3(256), 0, stream>>>(
            out, x, tf, ws, b1q, b2q, b1p, b2p);
    } else {
        // Fallback: out <- x, then 34 regular launches (kernel-boundary coherence).
        hipMemcpyAsync(out, x, (size_t)BATCH * NPTS * DIN * sizeof(float),
                       hipMemcpyDeviceToDevice, stream);
        float tq = 0.0f, tp = 0.0f;
        for (int h = 0; h < NSTEP; ++h) {
            const int phase = h & 1;
            const float dtmax = phase ? 0.25f : ((h == 0) ? 0.125f : 0.25f);
            const float tcur  = phase ? tp : tq;
            sympl_step<<<dim3(NBLK), dim3(256), 0, stream>>>(
                out, tf, ws, phase ? b1p : b1q, phase ? b2p : b2q,
                phase, tcur, dtmax);
            if (phase) tp += dtmax; else tq += dtmax;
        }
    }
}